// Round 4
// baseline (98.048 us; speedup 1.0000x reference)
//
#include <hip/hip_runtime.h>
#include <hip/hip_fp16.h>

#define NN 1024
#define HID 256
#define XD 128

typedef _Float16 h2 __attribute__((ext_vector_type(2)));
typedef _Float16 h8 __attribute__((ext_vector_type(8)));

// wsh (halves):
//   px  [0, 262144)       row-major [j][k]   (no b1)
//   py  [262144, 524288)  row-major [i][k]   (b1 folded in)
//   w2h [524288, 524544)
// wsf (floats) at byte 1049600:
#define WSF_BYTE_OFF 1049600
#define F_C    0      // 1024 : c[j] = exp(b2 - ls[j])
#define F_PART 1024   // 2048 : per (block, iset) exp-sum partials
#define F_T0P  3072   // 256  : per-prep-block T0 partials
#define F_LSP  3328   // 256  : per-prep-block ls partials

__device__ __forceinline__ h2 relu2(h2 x) {
  h2 z = {(_Float16)0, (_Float16)0};
  return __builtin_elementwise_max(x, z);
}

__device__ __forceinline__ float dot2f(h2 a, h2 b, float c) {
  return __builtin_amdgcn_fdot2(a, b, c, false);
}

__global__ __launch_bounds__(256) void prep_kernel(
    const float* __restrict__ x, const float* __restrict__ y,
    const float* __restrict__ W1, const float* __restrict__ b1,
    const float* __restrict__ w2, const float* __restrict__ b2p,
    const float* __restrict__ wb, const float* __restrict__ bbp,
    _Float16* __restrict__ wsh, float* __restrict__ wsf)
{
  __shared__ float sx[4][128];
  __shared__ float sy[4][128];
  __shared__ float st0[4][4];
  __shared__ float sls[4];
  const int t = threadIdx.x;
  const int blk = blockIdx.x;
  const int r0 = blk * 4;

  {
    const int rl = (t & 127) >> 5, f = t & 31;
    if (t < 128) {
      *(float4*)&sx[rl][f * 4] = *(const float4*)(x + (r0 + rl) * XD + f * 4);
    } else {
      *(float4*)&sy[rl][f * 4] = *(const float4*)(y + (r0 + rl) * XD + f * 4);
    }
  }
  __syncthreads();

  const int k = t;  // one hidden unit per thread
  float apx[4] = {0,0,0,0};
  float apy[4] = {0,0,0,0};
  const float* wrow = W1 + k * 256;
  for (int dq = 0; dq < 32; ++dq) {
    float4 wx = *(const float4*)(wrow + dq * 4);
    float4 wy = *(const float4*)(wrow + 128 + dq * 4);
#pragma unroll
    for (int r = 0; r < 4; ++r) {
      float4 xv = *(const float4*)&sx[r][dq * 4];
      float4 yv = *(const float4*)&sy[r][dq * 4];
      apx[r] = fmaf(xv.x, wx.x, apx[r]);
      apx[r] = fmaf(xv.y, wx.y, apx[r]);
      apx[r] = fmaf(xv.z, wx.z, apx[r]);
      apx[r] = fmaf(xv.w, wx.w, apx[r]);
      apy[r] = fmaf(yv.x, wy.x, apy[r]);
      apy[r] = fmaf(yv.y, wy.y, apy[r]);
      apy[r] = fmaf(yv.z, wy.z, apy[r]);
      apy[r] = fmaf(yv.w, wy.w, apy[r]);
    }
  }
  const float b1k = b1[k];
#pragma unroll
  for (int r = 0; r < 4; ++r) apy[r] += b1k;  // fold b1 into py

  // row-major f16 writes
  {
    _Float16* pxh = wsh;
    _Float16* pyh = wsh + 262144;
#pragma unroll
    for (int r = 0; r < 4; ++r) {
      const int j = r0 + r;
      pxh[j * 256 + k] = (_Float16)apx[r];
      pyh[j * 256 + k] = (_Float16)apy[r];
    }
  }

  // T0 partials (exact f32)
  const float w2k = w2[k];
  const float b2v = b2p[0];
  const int wv = t >> 6, lane = t & 63;
#pragma unroll
  for (int r = 0; r < 4; ++r) {
    float v = fmaxf(apx[r] + apy[r], 0.f) * w2k;
    for (int o = 32; o > 0; o >>= 1) v += __shfl_down(v, o);
    if (lane == 0) st0[wv][r] = v;
  }

  // ls[r] = y[r].wb + bb ; c[r] = exp(b2 - ls[r])
  if (t < 128) {
    const int rl = t >> 5, f = t & 31;
    float p = 0.f;
#pragma unroll
    for (int l = 0; l < 4; ++l) p = fmaf(sy[rl][f * 4 + l], wb[f * 4 + l], p);
    for (int m = 16; m > 0; m >>= 1) p += __shfl_xor(p, m);
    if (f == 0) {
      const float lsv = p + bbp[0];
      sls[rl] = lsv;
      wsf[F_C + r0 + rl] = __expf(b2v - lsv);
    }
  }
  __syncthreads();
  if (t == 0) {
    float t0s = 0.f, lss = 0.f;
#pragma unroll
    for (int r = 0; r < 4; ++r) {
      t0s += st0[0][r] + st0[1][r] + st0[2][r] + st0[3][r] + b2v;
      lss += sls[r];
    }
    wsf[F_T0P + blk] = t0s;
    wsf[F_LSP + blk] = lss;
  }
  if (blk == 0 && t < 128) {
    h2 wv2;
    wv2.x = (_Float16)w2[2 * t];
    wv2.y = (_Float16)w2[2 * t + 1];
    ((h2*)(wsh + 524288))[t] = wv2;
  }
}

// grid 512: blk = ig*16 + bj.  Block: 64 j (=lane) x 32 i (ig), K=256.
// Wave w: khalf = w>>2 (128 k), iset = w&3 (8 i).  px in regs, py/w2 via
// LDS broadcast.  khalf partials combined in-block via sComb.
__global__ __launch_bounds__(512, 4) void main_kernel(
    const _Float16* __restrict__ wsh, float* __restrict__ wsf)
{
  __shared__ _Float16 spy[32 * 256];   // 16 KB
  __shared__ _Float16 sw2[256];        // 512 B
  __shared__ float sComb[4][8][64];    // 8 KB
  const int t = threadIdx.x;
  const int lane = t & 63;
  const int w = t >> 6;
  const int blk = blockIdx.x;
  const int bj = blk & 15;
  const int i0 = (blk >> 4) * 32;
  const int khalf = w >> 2;
  const int iset = w & 3;

  // px -> regs: 128 halves (16 x dwordx4), issued before staging stores
  h8 pxr[16];
  {
    const float4* gpx = (const float4*)(wsh + (size_t)(bj * 64 + lane) * 256
                                            + khalf * 128);
#pragma unroll
    for (int it = 0; it < 16; ++it) ((float4*)pxr)[it] = gpx[it];
  }
  // cooperative stage: py rows i0..i0+32 (all k) + w2
  {
    const float4* gpy = (const float4*)(wsh + 262144 + (size_t)i0 * 256);
    float4* lpy = (float4*)spy;
    lpy[t] = gpy[t];
    lpy[t + 512] = gpy[t + 512];
    if (t < 32) ((float4*)sw2)[t] = ((const float4*)(wsh + 524288))[t];
  }
  __syncthreads();

  const float cj = wsf[F_C + bj * 64 + lane];

  const _Float16* w2k = sw2 + khalf * 128;
  float sacc[8];
#pragma unroll 2
  for (int ii = 0; ii < 8; ++ii) {
    const _Float16* prow = spy + (iset * 8 + ii) * 256 + khalf * 128;
    float s0 = 0.f, s1 = 0.f, s2 = 0.f, s3 = 0.f;
#pragma unroll
    for (int q = 0; q < 16; q += 4) {
#pragma unroll
      for (int u = 0; u < 4; ++u) {
        h8 pv = *(const h8*)(prow + (q + u) * 8);
        h8 wv = *(const h8*)(w2k + (q + u) * 8);
        const h2* p2 = (const h2*)&pv;
        const h2* w2p = (const h2*)&wv;
        const h2* x2 = (const h2*)&pxr[q + u];
        float s = (u == 0) ? s0 : (u == 1) ? s1 : (u == 2) ? s2 : s3;
        s = dot2f(relu2(x2[0] + p2[0]), w2p[0], s);
        s = dot2f(relu2(x2[1] + p2[1]), w2p[1], s);
        s = dot2f(relu2(x2[2] + p2[2]), w2p[2], s);
        s = dot2f(relu2(x2[3] + p2[3]), w2p[3], s);
        if (u == 0) s0 = s; else if (u == 1) s1 = s; else if (u == 2) s2 = s; else s3 = s;
      }
    }
    sacc[ii] = (s0 + s1) + (s2 + s3);
  }

  if (khalf == 1) {
#pragma unroll
    for (int ii = 0; ii < 8; ++ii) sComb[iset][ii][lane] = sacc[ii];
  }
  __syncthreads();
  if (khalf == 0) {
    float ts = 0.f;
#pragma unroll
    for (int ii = 0; ii < 8; ++ii)
      ts += __expf(sacc[ii] + sComb[iset][ii][lane]);
    ts *= cj;
    for (int o = 32; o > 0; o >>= 1) ts += __shfl_down(ts, o);
    if (lane == 0) wsf[F_PART + blk * 4 + iset] = ts;
  }
}

__global__ __launch_bounds__(256) void fin_kernel(
    const float* __restrict__ wsf, float* __restrict__ out)
{
  __shared__ float sr[4][3];
  const int t = threadIdx.x;
  float4 e0 = *(const float4*)(wsf + F_PART + t * 4);
  float4 e1 = *(const float4*)(wsf + F_PART + 1024 + t * 4);
  float e = (e0.x + e0.y + e0.z + e0.w) + (e1.x + e1.y + e1.z + e1.w);
  float t0 = wsf[F_T0P + t];
  float ls = wsf[F_LSP + t];
  for (int o = 32; o > 0; o >>= 1) {
    e  += __shfl_down(e, o);
    t0 += __shfl_down(t0, o);
    ls += __shfl_down(ls, o);
  }
  if ((t & 63) == 0) {
    sr[t >> 6][0] = e;
    sr[t >> 6][1] = t0;
    sr[t >> 6][2] = ls;
  }
  __syncthreads();
  if (t == 0) {
    const float es  = sr[0][0] + sr[1][0] + sr[2][0] + sr[3][0];
    const float t0s = sr[0][1] + sr[1][1] + sr[2][1] + sr[3][1];
    const float lss = sr[0][2] + sr[1][2] + sr[2][2] + sr[3][2];
    out[0] = 1.0f + t0s * (1.0f / 1024.0f) - lss * (1.0f / 1024.0f)
                  - es * (1.0f / 1048576.0f);
  }
}

extern "C" void kernel_launch(void* const* d_in, const int* in_sizes, int n_in,
                              void* d_out, int out_size, void* d_ws, size_t ws_size,
                              hipStream_t stream) {
  const float* x  = (const float*)d_in[0];
  const float* y  = (const float*)d_in[1];
  const float* W1 = (const float*)d_in[2];
  const float* b1 = (const float*)d_in[3];
  const float* w2 = (const float*)d_in[4];
  const float* b2 = (const float*)d_in[5];
  const float* wb = (const float*)d_in[6];
  const float* bb = (const float*)d_in[7];
  _Float16* wsh = (_Float16*)d_ws;
  float* wsf = (float*)((char*)d_ws + WSF_BYTE_OFF);
  float* out = (float*)d_out;

  hipLaunchKernelGGL(prep_kernel, dim3(256), dim3(256), 0, stream,
                     x, y, W1, b1, w2, b2, wb, bb, wsh, wsf);
  hipLaunchKernelGGL(main_kernel, dim3(512), dim3(512), 0, stream, wsh, wsf);
  hipLaunchKernelGGL(fin_kernel, dim3(1), dim3(256), 0, stream, wsf, out);
}

// Round 5
// 36.936 us; speedup vs baseline: 2.6546x; 2.6546x over previous
//
#include <hip/hip_runtime.h>
#include <hip/hip_fp16.h>

#define NN 1024
#define HID 256
#define XD 128

typedef _Float16 h2 __attribute__((ext_vector_type(2)));
typedef _Float16 h8 __attribute__((ext_vector_type(8)));

// wsh (halves):
//   pxT [0, 262144)       tiled [bj16][kq4][q8][lane64][kl8]  (coalesced h8 loads)
//   py  [262144, 524288)  row-major [i][k]   (b1 folded in)
//   w2h [524288, 524544)
// wsf (floats) at byte 1049600:
#define WSF_BYTE_OFF 1049600
#define F_C    0      // 1024 : c[j] = exp(b2 - ls[j])
#define F_PART 1024   // 4096 : per (block, kq) exp-sum partials
#define F_T0P  5120   // 256  : per-prep-block T0 partials
#define F_LSP  5376   // 256  : per-prep-block ls partials

__device__ __forceinline__ h2 relu2(h2 x) {
  h2 z = {(_Float16)0, (_Float16)0};
  return __builtin_elementwise_max(x, z);
}

__device__ __forceinline__ float dot2f(h2 a, h2 b, float c) {
  return __builtin_amdgcn_fdot2(a, b, c, false);
}

__global__ __launch_bounds__(256) void prep_kernel(
    const float* __restrict__ x, const float* __restrict__ y,
    const float* __restrict__ W1, const float* __restrict__ b1,
    const float* __restrict__ w2, const float* __restrict__ b2p,
    const float* __restrict__ wb, const float* __restrict__ bbp,
    _Float16* __restrict__ wsh, float* __restrict__ wsf)
{
  __shared__ float sx[4][128];
  __shared__ float sy[4][128];
  __shared__ float st0[4][4];
  __shared__ float sls[4];
  const int t = threadIdx.x;
  const int blk = blockIdx.x;
  const int r0 = blk * 4;

  {
    const int rl = (t & 127) >> 5, f = t & 31;
    if (t < 128) {
      *(float4*)&sx[rl][f * 4] = *(const float4*)(x + (r0 + rl) * XD + f * 4);
    } else {
      *(float4*)&sy[rl][f * 4] = *(const float4*)(y + (r0 + rl) * XD + f * 4);
    }
  }
  __syncthreads();

  const int k = t;  // one hidden unit per thread
  float apx[4] = {0,0,0,0};
  float apy[4] = {0,0,0,0};
  const float* wrow = W1 + k * 256;
  for (int dq = 0; dq < 32; ++dq) {
    float4 wx = *(const float4*)(wrow + dq * 4);
    float4 wy = *(const float4*)(wrow + 128 + dq * 4);
#pragma unroll
    for (int r = 0; r < 4; ++r) {
      float4 xv = *(const float4*)&sx[r][dq * 4];
      float4 yv = *(const float4*)&sy[r][dq * 4];
      apx[r] = fmaf(xv.x, wx.x, apx[r]);
      apx[r] = fmaf(xv.y, wx.y, apx[r]);
      apx[r] = fmaf(xv.z, wx.z, apx[r]);
      apx[r] = fmaf(xv.w, wx.w, apx[r]);
      apy[r] = fmaf(yv.x, wy.x, apy[r]);
      apy[r] = fmaf(yv.y, wy.y, apy[r]);
      apy[r] = fmaf(yv.z, wy.z, apy[r]);
      apy[r] = fmaf(yv.w, wy.w, apy[r]);
    }
  }
  const float b1k = b1[k];
#pragma unroll
  for (int r = 0; r < 4; ++r) apy[r] += b1k;  // fold b1 into py

  // px: transposed tile layout; py: row-major
  {
    _Float16* pxh = wsh;
    _Float16* pyh = wsh + 262144;
    const int kq = k >> 6, q = (k >> 3) & 7, kl = k & 7;
#pragma unroll
    for (int r = 0; r < 4; ++r) {
      const int j = r0 + r;
      pxh[(j >> 6) * 16384 + kq * 4096 + q * 512 + (j & 63) * 8 + kl]
          = (_Float16)apx[r];
      pyh[j * 256 + k] = (_Float16)apy[r];
    }
  }

  // T0 partials (exact f32)
  const float w2k = w2[k];
  const float b2v = b2p[0];
  const int wv = t >> 6, lane = t & 63;
#pragma unroll
  for (int r = 0; r < 4; ++r) {
    float v = fmaxf(apx[r] + apy[r], 0.f) * w2k;
    for (int o = 32; o > 0; o >>= 1) v += __shfl_down(v, o);
    if (lane == 0) st0[wv][r] = v;
  }

  // ls[r] = y[r].wb + bb ; c[r] = exp(b2 - ls[r])
  if (t < 128) {
    const int rl = t >> 5, f = t & 31;
    float p = 0.f;
#pragma unroll
    for (int l = 0; l < 4; ++l) p = fmaf(sy[rl][f * 4 + l], wb[f * 4 + l], p);
    for (int m = 16; m > 0; m >>= 1) p += __shfl_xor(p, m);
    if (f == 0) {
      const float lsv = p + bbp[0];
      sls[rl] = lsv;
      wsf[F_C + r0 + rl] = __expf(b2v - lsv);
    }
  }
  __syncthreads();
  if (t == 0) {
    float t0s = 0.f, lss = 0.f;
#pragma unroll
    for (int r = 0; r < 4; ++r) {
      t0s += st0[0][r] + st0[1][r] + st0[2][r] + st0[3][r] + b2v;
      lss += sls[r];
    }
    wsf[F_T0P + blk] = t0s;
    wsf[F_LSP + blk] = lss;
  }
  if (blk == 0 && t < 128) {
    h2 wv2;
    wv2.x = (_Float16)w2[2 * t];
    wv2.y = (_Float16)w2[2 * t + 1];
    ((h2*)(wsh + 524288))[t] = wv2;
  }
}

// grid 1024: blk = ib*16 + bj.  Block tile: 64 j (=lane) x 16 i, K=256.
// Wave w = kq (k-quarter, 64 k).  px chunk in 32 VGPRs (coalesced loads from
// pxT), w2 chunk in 32 VGPRs, py via LDS broadcast reads.  kq partials
// combined in-block through sComb, then exp * c_j.
__global__ __launch_bounds__(256, 4) void main_kernel(
    const _Float16* __restrict__ wsh, float* __restrict__ wsf)
{
  __shared__ _Float16 spy[16 * 256];   // 8 KB
  __shared__ _Float16 sw2[256];        // 512 B
  __shared__ float sComb[4][16][64];   // 16 KB
  const int t = threadIdx.x;
  const int lane = t & 63;
  const int kq = t >> 6;
  const int blk = blockIdx.x;
  const int bj = blk & 15;
  const int i0 = (blk >> 4) * 16;

  // px chunk -> regs: fully coalesced dwordx4 from transposed layout
  h8 pxr[8];
  {
    const float4* gpx = (const float4*)(wsh + bj * 16384 + kq * 4096);
#pragma unroll
    for (int q = 0; q < 8; ++q) ((float4*)pxr)[q] = gpx[q * 64 + lane];
  }
  // stage py rows [i0, i0+16) all k, + w2
  {
    const float4* gpy = (const float4*)(wsh + 262144 + (size_t)i0 * 256);
    ((float4*)spy)[t] = gpy[t];
    ((float4*)spy)[t + 256] = gpy[t + 256];
    if (t < 32) ((float4*)sw2)[t] = ((const float4*)(wsh + 524288))[t];
  }
  __syncthreads();

  h8 w2r[8];
#pragma unroll
  for (int q = 0; q < 8; ++q) w2r[q] = ((const h8*)(sw2 + kq * 64))[q];

  float acc[16];
#pragma unroll
  for (int ii = 0; ii < 16; ++ii) {
    const h8* prow = (const h8*)(spy + ii * 256 + kq * 64);
    float sa[4] = {0.f, 0.f, 0.f, 0.f};
#pragma unroll
    for (int q = 0; q < 8; ++q) {
      h8 pv = prow[q];                    // broadcast ds_read_b128
      const h2* p2 = (const h2*)&pv;
      const h2* x2 = (const h2*)&pxr[q];
      const h2* wp = (const h2*)&w2r[q];
      float s = sa[q & 3];
      s = dot2f(relu2(x2[0] + p2[0]), wp[0], s);
      s = dot2f(relu2(x2[1] + p2[1]), wp[1], s);
      s = dot2f(relu2(x2[2] + p2[2]), wp[2], s);
      s = dot2f(relu2(x2[3] + p2[3]), wp[3], s);
      sa[q & 3] = s;
    }
    acc[ii] = (sa[0] + sa[1]) + (sa[2] + sa[3]);
  }

#pragma unroll
  for (int ii = 0; ii < 16; ++ii) sComb[kq][ii][lane] = acc[ii];
  __syncthreads();

  const float cj = wsf[F_C + bj * 64 + lane];
  float ts = 0.f;
#pragma unroll
  for (int r = 0; r < 4; ++r) {
    const int ii = kq * 4 + r;
    float s = (sComb[0][ii][lane] + sComb[1][ii][lane])
            + (sComb[2][ii][lane] + sComb[3][ii][lane]);
    ts += __expf(s);
  }
  ts *= cj;
  for (int o = 32; o > 0; o >>= 1) ts += __shfl_down(ts, o);
  if (lane == 0) wsf[F_PART + blk * 4 + kq] = ts;
}

__global__ __launch_bounds__(256) void fin_kernel(
    const float* __restrict__ wsf, float* __restrict__ out)
{
  __shared__ float sr[4][3];
  const int t = threadIdx.x;
  float e = 0.f;
  const float4* pp = (const float4*)(wsf + F_PART);
#pragma unroll
  for (int s = 0; s < 4; ++s) {
    float4 ev = pp[t * 4 + s];
    e += (ev.x + ev.y) + (ev.z + ev.w);
  }
  float t0 = wsf[F_T0P + t];
  float ls = wsf[F_LSP + t];
  for (int o = 32; o > 0; o >>= 1) {
    e  += __shfl_down(e, o);
    t0 += __shfl_down(t0, o);
    ls += __shfl_down(ls, o);
  }
  if ((t & 63) == 0) {
    sr[t >> 6][0] = e;
    sr[t >> 6][1] = t0;
    sr[t >> 6][2] = ls;
  }
  __syncthreads();
  if (t == 0) {
    const float es  = sr[0][0] + sr[1][0] + sr[2][0] + sr[3][0];
    const float t0s = sr[0][1] + sr[1][1] + sr[2][1] + sr[3][1];
    const float lss = sr[0][2] + sr[1][2] + sr[2][2] + sr[3][2];
    out[0] = 1.0f + t0s * (1.0f / 1024.0f) - lss * (1.0f / 1024.0f)
                  - es * (1.0f / 1048576.0f);
  }
}

extern "C" void kernel_launch(void* const* d_in, const int* in_sizes, int n_in,
                              void* d_out, int out_size, void* d_ws, size_t ws_size,
                              hipStream_t stream) {
  const float* x  = (const float*)d_in[0];
  const float* y  = (const float*)d_in[1];
  const float* W1 = (const float*)d_in[2];
  const float* b1 = (const float*)d_in[3];
  const float* w2 = (const float*)d_in[4];
  const float* b2 = (const float*)d_in[5];
  const float* wb = (const float*)d_in[6];
  const float* bb = (const float*)d_in[7];
  _Float16* wsh = (_Float16*)d_ws;
  float* wsf = (float*)((char*)d_ws + WSF_BYTE_OFF);
  float* out = (float*)d_out;

  hipLaunchKernelGGL(prep_kernel, dim3(256), dim3(256), 0, stream,
                     x, y, W1, b1, w2, b2, wb, bb, wsh, wsf);
  hipLaunchKernelGGL(main_kernel, dim3(1024), dim3(256), 0, stream, wsh, wsf);
  hipLaunchKernelGGL(fin_kernel, dim3(1), dim3(256), 0, stream, wsf, out);
}

// Round 6
// 35.683 us; speedup vs baseline: 2.7478x; 1.0351x over previous
//
#include <hip/hip_runtime.h>
#include <hip/hip_fp16.h>

#define NN 1024
#define HID 256
#define XD 128

typedef _Float16 h2 __attribute__((ext_vector_type(2)));
typedef _Float16 h8 __attribute__((ext_vector_type(8)));

// wsh (halves):
//   pxT [0, 262144)  tiled: idx = ((jt*8+kg)*8 + ks*2+jj)*512 + lane*8 + kl
//       jt=j>>7, jj=(j>>6)&1, lane=j&63, kg=k>>5, ks=(k>>3)&3, kl=k&7
//   py  [262144, 524288)  row-major [i][k]  (b1 folded in)
//   w2h [524288, 524544)
// wsf (floats) at byte 1049600:
#define WSF_BYTE_OFF 1049600
#define F_C    0      // 1024 : c[j] = exp(b2 - ls[j])
#define F_PART 1024   // 512  : per-block exp-sum partials
#define F_T0P  5120   // 256  : per-prep-block T0 partials
#define F_LSP  5376   // 256  : per-prep-block ls partials

__device__ __forceinline__ h2 relu2(h2 x) {
  h2 z = {(_Float16)0, (_Float16)0};
  return __builtin_elementwise_max(x, z);
}

__device__ __forceinline__ float dot2f(h2 a, h2 b, float c) {
  return __builtin_amdgcn_fdot2(a, b, c, false);
}

__global__ __launch_bounds__(256) void prep_kernel(
    const float* __restrict__ x, const float* __restrict__ y,
    const float* __restrict__ W1, const float* __restrict__ b1,
    const float* __restrict__ w2, const float* __restrict__ b2p,
    const float* __restrict__ wb, const float* __restrict__ bbp,
    _Float16* __restrict__ wsh, float* __restrict__ wsf)
{
  __shared__ float sx[4][128];
  __shared__ float sy[4][128];
  __shared__ float st0[4][4];
  __shared__ float sls[4];
  const int t = threadIdx.x;
  const int blk = blockIdx.x;
  const int r0 = blk * 4;

  {
    const int rl = (t & 127) >> 5, f = t & 31;
    if (t < 128) {
      *(float4*)&sx[rl][f * 4] = *(const float4*)(x + (r0 + rl) * XD + f * 4);
    } else {
      *(float4*)&sy[rl][f * 4] = *(const float4*)(y + (r0 + rl) * XD + f * 4);
    }
  }
  __syncthreads();

  const int k = t;  // one hidden unit per thread
  float apx[4] = {0,0,0,0};
  float apy[4] = {0,0,0,0};
  const float* wrow = W1 + k * 256;
  for (int dq = 0; dq < 32; ++dq) {
    float4 wx = *(const float4*)(wrow + dq * 4);
    float4 wy = *(const float4*)(wrow + 128 + dq * 4);
#pragma unroll
    for (int r = 0; r < 4; ++r) {
      float4 xv = *(const float4*)&sx[r][dq * 4];
      float4 yv = *(const float4*)&sy[r][dq * 4];
      apx[r] = fmaf(xv.x, wx.x, apx[r]);
      apx[r] = fmaf(xv.y, wx.y, apx[r]);
      apx[r] = fmaf(xv.z, wx.z, apx[r]);
      apx[r] = fmaf(xv.w, wx.w, apx[r]);
      apy[r] = fmaf(yv.x, wy.x, apy[r]);
      apy[r] = fmaf(yv.y, wy.y, apy[r]);
      apy[r] = fmaf(yv.z, wy.z, apy[r]);
      apy[r] = fmaf(yv.w, wy.w, apy[r]);
    }
  }
  const float b1k = b1[k];
#pragma unroll
  for (int r = 0; r < 4; ++r) apy[r] += b1k;  // fold b1 into py

  // px: transposed tile layout (see header); py: row-major
  {
    _Float16* pxh = wsh;
    _Float16* pyh = wsh + 262144;
    const int kg = k >> 5, ks = (k >> 3) & 3, kl = k & 7;
#pragma unroll
    for (int r = 0; r < 4; ++r) {
      const int j = r0 + r;
      const int jt = j >> 7, jj = (j >> 6) & 1, ln = j & 63;
      pxh[((jt * 8 + kg) * 8 + ks * 2 + jj) * 512 + ln * 8 + kl]
          = (_Float16)apx[r];
      pyh[j * 256 + k] = (_Float16)apy[r];
    }
  }

  // T0 partials (exact f32)
  const float w2k = w2[k];
  const float b2v = b2p[0];
  const int wv = t >> 6, lane = t & 63;
#pragma unroll
  for (int r = 0; r < 4; ++r) {
    float v = fmaxf(apx[r] + apy[r], 0.f) * w2k;
    for (int o = 32; o > 0; o >>= 1) v += __shfl_down(v, o);
    if (lane == 0) st0[wv][r] = v;
  }

  // ls[r] = y[r].wb + bb ; c[r] = exp(b2 - ls[r])
  if (t < 128) {
    const int rl = t >> 5, f = t & 31;
    float p = 0.f;
#pragma unroll
    for (int l = 0; l < 4; ++l) p = fmaf(sy[rl][f * 4 + l], wb[f * 4 + l], p);
    for (int m = 16; m > 0; m >>= 1) p += __shfl_xor(p, m);
    if (f == 0) {
      const float lsv = p + bbp[0];
      sls[rl] = lsv;
      wsf[F_C + r0 + rl] = __expf(b2v - lsv);
    }
  }
  __syncthreads();
  if (t == 0) {
    float t0s = 0.f, lss = 0.f;
#pragma unroll
    for (int r = 0; r < 4; ++r) {
      t0s += st0[0][r] + st0[1][r] + st0[2][r] + st0[3][r] + b2v;
      lss += sls[r];
    }
    wsf[F_T0P + blk] = t0s;
    wsf[F_LSP + blk] = lss;
  }
  if (blk == 0 && t < 128) {
    h2 wv2;
    wv2.x = (_Float16)w2[2 * t];
    wv2.y = (_Float16)w2[2 * t + 1];
    ((h2*)(wsh + 524288))[t] = wv2;
  }
}

// grid 512: blk = bi*8 + bj.  Block tile: 128 j (2 per lane) x 16 i, K=256.
// 8 waves; wave w = kg (32 k).  px chunk 32 VGPR, w2 chunk 16 VGPR, py via
// LDS broadcast (1 b128 per 24 VALU instrs).  kg partials combined by a
// 3-round LDS tree, then wave 0 does exp * c_j and the block reduction.
__global__ __launch_bounds__(512) void main_kernel(
    const _Float16* __restrict__ wsh, float* __restrict__ wsf)
{
  __shared__ _Float16 spy[16 * 256];   // 8 KB
  __shared__ _Float16 sw2[256];        // 512 B
  __shared__ float sComb[4][16][128];  // 32 KB
  const int t = threadIdx.x;
  const int lane = t & 63;
  const int kg = t >> 6;               // 0..7
  const int blk = blockIdx.x;
  const int bj = blk & 7;              // j0 = bj*128
  const int i0 = (blk >> 3) * 16;

  // px chunk -> regs: 8 coalesced dwordx4 (2 j x 32 k per lane)
  h8 pxr[8];
  {
    const float4* gpx = (const float4*)wsh + ((bj * 8 + kg) * 8) * 64 + lane;
#pragma unroll
    for (int q = 0; q < 8; ++q) ((float4*)pxr)[q] = gpx[q * 64];
  }
  // stage py tile (16 rows x 256 k = 512 float4) + w2
  {
    const float4* gpy = (const float4*)(wsh + 262144 + (size_t)i0 * 256);
    ((float4*)spy)[t] = gpy[t];
    if (t < 32) ((float4*)sw2)[t] = ((const float4*)(wsh + 524288))[t];
  }
  __syncthreads();

  h8 w2r[4];
#pragma unroll
  for (int q = 0; q < 4; ++q) w2r[q] = ((const h8*)(sw2 + kg * 32))[q];

  float acc[16][2];
#pragma unroll
  for (int ii = 0; ii < 16; ++ii) { acc[ii][0] = 0.f; acc[ii][1] = 0.f; }

#pragma unroll
  for (int ii = 0; ii < 16; ++ii) {
    const h8* prow = (const h8*)(spy + ii * 256 + kg * 32);
#pragma unroll
    for (int ks = 0; ks < 4; ++ks) {
      h8 pv = prow[ks];                 // broadcast ds_read_b128
      const h2* p2 = (const h2*)&pv;
      const h2* wp = (const h2*)&w2r[ks];
#pragma unroll
      for (int jj = 0; jj < 2; ++jj) {
        const h2* x2 = (const h2*)&pxr[ks * 2 + jj];
        float s = acc[ii][jj];
        s = dot2f(relu2(x2[0] + p2[0]), wp[0], s);
        s = dot2f(relu2(x2[1] + p2[1]), wp[1], s);
        s = dot2f(relu2(x2[2] + p2[2]), wp[2], s);
        s = dot2f(relu2(x2[3] + p2[3]), wp[3], s);
        acc[ii][jj] = s;
      }
    }
  }

  // 3-round tree combine of the 8 kg partials
  if (kg >= 4) {
#pragma unroll
    for (int ii = 0; ii < 16; ++ii) {
      sComb[kg - 4][ii][lane]      = acc[ii][0];
      sComb[kg - 4][ii][lane + 64] = acc[ii][1];
    }
  }
  __syncthreads();
  if (kg < 4) {
#pragma unroll
    for (int ii = 0; ii < 16; ++ii) {
      acc[ii][0] += sComb[kg][ii][lane];
      acc[ii][1] += sComb[kg][ii][lane + 64];
    }
  }
  __syncthreads();
  if (kg == 2 || kg == 3) {
#pragma unroll
    for (int ii = 0; ii < 16; ++ii) {
      sComb[kg - 2][ii][lane]      = acc[ii][0];
      sComb[kg - 2][ii][lane + 64] = acc[ii][1];
    }
  }
  __syncthreads();
  if (kg < 2) {
#pragma unroll
    for (int ii = 0; ii < 16; ++ii) {
      acc[ii][0] += sComb[kg][ii][lane];
      acc[ii][1] += sComb[kg][ii][lane + 64];
    }
  }
  __syncthreads();
  if (kg == 1) {
#pragma unroll
    for (int ii = 0; ii < 16; ++ii) {
      sComb[0][ii][lane]      = acc[ii][0];
      sComb[0][ii][lane + 64] = acc[ii][1];
    }
  }
  __syncthreads();
  if (kg == 0) {
    const float* cbase = wsf + F_C + bj * 128;
    const float c0 = cbase[lane], c1 = cbase[64 + lane];
    float ts = 0.f;
#pragma unroll
    for (int ii = 0; ii < 16; ++ii) {
      ts += __expf(acc[ii][0] + sComb[0][ii][lane]) * c0;
      ts += __expf(acc[ii][1] + sComb[0][ii][lane + 64]) * c1;
    }
    for (int o = 32; o > 0; o >>= 1) ts += __shfl_down(ts, o);
    if (lane == 0) wsf[F_PART + blk] = ts;
  }
}

__global__ __launch_bounds__(256) void fin_kernel(
    const float* __restrict__ wsf, float* __restrict__ out)
{
  __shared__ float sr[4][3];
  const int t = threadIdx.x;
  float e = 0.f;
  if (t < 128) {
    float4 ev = ((const float4*)(wsf + F_PART))[t];
    e = (ev.x + ev.y) + (ev.z + ev.w);
  }
  float t0 = wsf[F_T0P + t];
  float ls = wsf[F_LSP + t];
  for (int o = 32; o > 0; o >>= 1) {
    e  += __shfl_down(e, o);
    t0 += __shfl_down(t0, o);
    ls += __shfl_down(ls, o);
  }
  if ((t & 63) == 0) {
    sr[t >> 6][0] = e;
    sr[t >> 6][1] = t0;
    sr[t >> 6][2] = ls;
  }
  __syncthreads();
  if (t == 0) {
    const float es  = sr[0][0] + sr[1][0] + sr[2][0] + sr[3][0];
    const float t0s = sr[0][1] + sr[1][1] + sr[2][1] + sr[3][1];
    const float lss = sr[0][2] + sr[1][2] + sr[2][2] + sr[3][2];
    out[0] = 1.0f + t0s * (1.0f / 1024.0f) - lss * (1.0f / 1024.0f)
                  - es * (1.0f / 1048576.0f);
  }
}

extern "C" void kernel_launch(void* const* d_in, const int* in_sizes, int n_in,
                              void* d_out, int out_size, void* d_ws, size_t ws_size,
                              hipStream_t stream) {
  const float* x  = (const float*)d_in[0];
  const float* y  = (const float*)d_in[1];
  const float* W1 = (const float*)d_in[2];
  const float* b1 = (const float*)d_in[3];
  const float* w2 = (const float*)d_in[4];
  const float* b2 = (const float*)d_in[5];
  const float* wb = (const float*)d_in[6];
  const float* bb = (const float*)d_in[7];
  _Float16* wsh = (_Float16*)d_ws;
  float* wsf = (float*)((char*)d_ws + WSF_BYTE_OFF);
  float* out = (float*)d_out;

  hipLaunchKernelGGL(prep_kernel, dim3(256), dim3(256), 0, stream,
                     x, y, W1, b1, w2, b2, wb, bb, wsh, wsf);
  hipLaunchKernelGGL(main_kernel, dim3(512), dim3(512), 0, stream, wsh, wsf);
  hipLaunchKernelGGL(fin_kernel, dim3(1), dim3(256), 0, stream, wsf, out);
}